// Round 12
// baseline (714.490 us; speedup 1.0000x reference)
//
#include <hip/hip_runtime.h>
#include <hip/hip_bf16.h>

#define HC 252
#define WC 252
#define CD 256
#define NHEADS 16

// XPT padded image, TRANSPOSED: [b][h 0..251][wp 0..263][ci 0..255], wp = w_img + 4
#define XP_W 264
#define XP_ROW (XP_W*256)            // u16 per (b,h) row: 67584
#define XP_BH  (252*XP_ROW)          // u16 per b

typedef unsigned short u16;
typedef unsigned int u32;
typedef __attribute__((ext_vector_type(8))) short bf16x8;
typedef __attribute__((ext_vector_type(4))) float f32x4;
typedef __attribute__((ext_vector_type(4))) u32 u32x4;
typedef __attribute__((ext_vector_type(2))) u32 u32x2;

// ---- workspace layout (bytes) ----
#define XP_BYTES (2u * 2u * (unsigned)XP_BH)       // 68,124,672
#define ZP_OFF   XP_BYTES
#define ZP_BYTES 409600u
#define WT_OFF   (ZP_OFF + ZP_BYTES)
#define WT_ELEMS (128*8192)                        // [s][l(swz)][8], k=(tap,ci) order
#define WPW_OFF  (WT_OFF + (unsigned)WT_ELEMS*2u)
#define WPW_ELEMS (8*8192)
#define WQ_OFF   (WPW_OFF + (unsigned)WPW_ELEMS*2u)
#define WQ_ELEMS (768*256)
#define BIAS_OFF (WQ_OFF + (unsigned)WQ_ELEMS*2u)

__device__ __forceinline__ u16 bfu(float f) {
    __hip_bfloat16 h = __float2bfloat16(f);
    return *(reinterpret_cast<u16*>(&h));
}
__device__ __forceinline__ u32 pack2(float a, float b) {
    return (u32)bfu(a) | ((u32)bfu(b) << 16);
}
__device__ __forceinline__ float bf2f(u16 v) {
    union { u32 u; float f; } cv; cv.u = ((u32)v) << 16; return cv.f;
}

// ---------------- Kernel A: fused qkv + window attention (MFMA) --------------
// grid 2048 (XCD-swizzled), 256 threads (4 waves, 4 heads/wave, sequential).
__global__ __launch_bounds__(256, 2) void attn_mfma(
    const float* __restrict__ x, const u16* __restrict__ WQ,
    const float* __restrict__ BIASF, u16* __restrict__ xp)
{
    __shared__ __align__(16) char smem[73728];

    const int bid = blockIdx.x;
    const int zz = (bid & 7) * 256 + (bid >> 3);   // XCD-bijective swizzle
    const int wx = zz & 31, wy = (zz >> 5) & 31, b = zz >> 10;
    const int tid = threadIdx.x;
    const int lane = tid & 63, wid = tid >> 6;
    const int g = lane >> 4, li = lane & 15;

    // ---- stage Xwin (fp32 x -> bf16 LDS, transposed, reflect-padded) ----
    {
        int ci = tid;
        const float* srcc = x + (size_t)(b * 256 + ci) * (HC * WC);
        #pragma unroll
        for (int r = 0; r < 8; ++r) {
            int h = wy * 8 + r; if (h >= HC) h = 2 * HC - 2 - h;
            const float* src = srcc + h * WC;
            float v[8];
            if (wx == 31) {
                #pragma unroll
                for (int c = 0; c < 8; ++c) {
                    int w = 248 + c; if (w >= WC) w = 2 * WC - 2 - w;
                    v[c] = src[w];
                }
            } else {
                float4 f0 = *(const float4*)(src + wx * 8);
                float4 f1 = *(const float4*)(src + wx * 8 + 4);
                v[0]=f0.x; v[1]=f0.y; v[2]=f0.z; v[3]=f0.w;
                v[4]=f1.x; v[5]=f1.y; v[6]=f1.z; v[7]=f1.w;
            }
            #pragma unroll
            for (int c = 0; c < 8; ++c) {
                int pos = r * 8 + c;
                int byte = pos * 512 + ((ci * 2) ^ ((pos & 7) << 4));
                *(u16*)(smem + byte) = bfu(v[c]);
            }
        }
    }
    __syncthreads();

    const int WB = 32768 + wid * 10240;
    char* Qb = smem + WB;
    char* Kb = smem + WB + 2048;
    char* Vb = smem + WB + 4096;
    char* Pb = smem + WB + 6144;

    const bf16x8 zf = {0,0,0,0,0,0,0,0};

    #pragma unroll 1
    for (int hh = 0; hh < 4; ++hh) {
        const int head = wid * 4 + hh;

        f32x4 acc[3][4];
        #pragma unroll
        for (int p = 0; p < 3; ++p)
            #pragma unroll
            for (int nf = 0; nf < 4; ++nf) acc[p][nf] = (f32x4){0.f,0.f,0.f,0.f};

        for (int ks = 0; ks < 8; ++ks) {
            bf16x8 bx[4];
            #pragma unroll
            for (int nf = 0; nf < 4; ++nf) {
                int pos = 16 * nf + li;
                int byte = pos * 512 + ((ks * 64 + 16 * g) ^ ((pos & 7) << 4));
                bx[nf] = *(const bf16x8*)(smem + byte);
            }
            bf16x8 aw[3];
            #pragma unroll
            for (int p = 0; p < 3; ++p) {
                int o = p * 256 + head * 16 + li;
                aw[p] = *(const bf16x8*)(WQ + o * 256 + ks * 32 + 8 * g);
            }
            __builtin_amdgcn_s_setprio(1);
            #pragma unroll
            for (int p = 0; p < 3; ++p)
                #pragma unroll
                for (int nf = 0; nf < 4; ++nf)
                    acc[p][nf] = __builtin_amdgcn_mfma_f32_16x16x32_bf16(aw[p], bx[nf], acc[p][nf], 0, 0, 0);
            __builtin_amdgcn_s_setprio(0);
        }

        #pragma unroll
        for (int p = 0; p < 3; ++p) {
            if (p < 2) {
                char* base = (p == 0) ? Qb : Kb;
                #pragma unroll
                for (int nf = 0; nf < 4; ++nf) {
                    int pos = 16 * nf + li;
                    u32 lo = pack2(acc[p][nf][0], acc[p][nf][1]);
                    u32 hi = pack2(acc[p][nf][2], acc[p][nf][3]);
                    int byte = pos * 32 + ((8 * g) ^ (((pos >> 2) & 1) << 4));
                    *(u32x2*)(base + byte) = (u32x2){lo, hi};
                }
            } else {
                #pragma unroll
                for (int nf = 0; nf < 4; ++nf) {
                    int pos = 16 * nf + li;
                    #pragma unroll
                    for (int r = 0; r < 4; ++r) {
                        int d = 4 * g + r;
                        int byte = (pos >> 3) * 256 + d * 16 + (pos & 7) * 2;
                        *(u16*)(Vb + byte) = bfu(acc[p][nf][r]);
                    }
                }
            }
        }

        f32x4 s[4][4];
        #pragma unroll
        for (int mf = 0; mf < 4; ++mf)
            #pragma unroll
            for (int nf = 0; nf < 4; ++nf) s[mf][nf] = (f32x4){0.f,0.f,0.f,0.f};
        bf16x8 bk[4];
        #pragma unroll
        for (int nf = 0; nf < 4; ++nf) {
            int pos = 16 * nf + li;
            bk[nf] = (g < 2) ? *(const bf16x8*)(Kb + pos * 32 + ((16 * g) ^ (((pos >> 2) & 1) << 4))) : zf;
        }
        __builtin_amdgcn_s_setprio(1);
        #pragma unroll
        for (int mf = 0; mf < 4; ++mf) {
            int pos = 16 * mf + li;
            bf16x8 aq = (g < 2) ? *(const bf16x8*)(Qb + pos * 32 + ((16 * g) ^ (((pos >> 2) & 1) << 4))) : zf;
            #pragma unroll
            for (int nf = 0; nf < 4; ++nf)
                s[mf][nf] = __builtin_amdgcn_mfma_f32_16x16x32_bf16(aq, bk[nf], s[mf][nf], 0, 0, 0);
        }
        __builtin_amdgcn_s_setprio(0);

        f32x4 e[4][4];
        f32x4 rs[4];
        #pragma unroll
        for (int mf = 0; mf < 4; ++mf) rs[mf] = (f32x4){0.f,0.f,0.f,0.f};
        #pragma unroll
        for (int mf = 0; mf < 4; ++mf)
            #pragma unroll
            for (int nf = 0; nf < 4; ++nf) {
                f32x4 b4 = *(const f32x4*)(BIASF + (((head * 4 + mf) * 4 + nf) * 64 + lane) * 4);
                #pragma unroll
                for (int r = 0; r < 4; ++r) {
                    float ev = __expf(s[mf][nf][r] * 0.25f + b4[r]);
                    e[mf][nf][r] = ev;
                    rs[mf][r] += ev;
                }
            }
        #pragma unroll
        for (int mf = 0; mf < 4; ++mf)
            #pragma unroll
            for (int r = 0; r < 4; ++r) {
                float t = rs[mf][r];
                t += __shfl_xor(t, 1); t += __shfl_xor(t, 2);
                t += __shfl_xor(t, 4); t += __shfl_xor(t, 8);
                rs[mf][r] = t;
            }

        f32x4 o[4];
        #pragma unroll
        for (int mf = 0; mf < 4; ++mf) o[mf] = (f32x4){0.f,0.f,0.f,0.f};
        const bool even = !(lane & 1);
        #pragma unroll
        for (int hf = 0; hf < 2; ++hf) {
            #pragma unroll
            for (int mf = 0; mf < 4; ++mf)
                #pragma unroll
                for (int nfl = 0; nfl < 2; ++nfl) {
                    f32x4 ee = e[mf][2 * hf + nfl];
                    float p0 = __shfl_xor(ee[0], 1), p1 = __shfl_xor(ee[1], 1);
                    float p2 = __shfl_xor(ee[2], 1), p3 = __shfl_xor(ee[3], 1);
                    int jl = 16 * nfl + (li & ~1);
                    u32 w0, w1; int r0;
                    if (even) { w0 = pack2(ee[0], p0); w1 = pack2(ee[1], p1); r0 = 0; }
                    else      { w0 = pack2(p2, ee[2]); w1 = pack2(p3, ee[3]); r0 = 2; }
                    int i0 = 16 * mf + 4 * g + r0, i1 = i0 + 1;
                    *(u32*)(Pb + i0 * 64 + ((2 * jl) ^ ((i0 & 3) << 4))) = w0;
                    *(u32*)(Pb + i1 * 64 + ((2 * jl) ^ ((i1 & 3) << 4))) = w1;
                }
            bf16x8 bv = *(const bf16x8*)(Vb + (4 * hf + g) * 256 + li * 16);
            __builtin_amdgcn_s_setprio(1);
            #pragma unroll
            for (int mf = 0; mf < 4; ++mf) {
                int i = 16 * mf + li;
                bf16x8 ap = *(const bf16x8*)(Pb + i * 64 + ((16 * g) ^ ((i & 3) << 4)));
                o[mf] = __builtin_amdgcn_mfma_f32_16x16x32_bf16(ap, bv, o[mf], 0, 0, 0);
            }
            __builtin_amdgcn_s_setprio(0);
        }

        // ---- store into XPT[b][h][wp][ci] ----
        #pragma unroll
        for (int mf = 0; mf < 4; ++mf) {
            int h = wy * 8 + 2 * mf + (g >> 1);
            int wbase = wx * 8 + 4 * (g & 1);
            if (h < HC && wbase < WC) {
                size_t rowb = ((size_t)(b * HC + h)) * XP_ROW + (size_t)(head * 16 + li);
                #pragma unroll
                for (int r = 0; r < 4; ++r) {
                    float v = o[mf][r] / rs[mf][r];
                    xp[rowb + (size_t)(wbase + r + 4) * 256] = bfu(v);
                }
            }
        }
    }
}

// ---------------- weight prep: WT (k=(tap,ci), pre-swizzled), WP, ZP, WQ, BIASF
__global__ __launch_bounds__(256) void wprep_kernel(
    const float* __restrict__ wh, const float* __restrict__ wv,
    const float* __restrict__ wpw, const float* __restrict__ wqkv,
    const float* __restrict__ btab, u16* __restrict__ wsu)
{
    int i = blockIdx.x * 256 + threadIdx.x;
    u16* WT = wsu + WT_OFF / 2;
    u16* WP = wsu + WPW_OFF / 2;
    u16* ZP = wsu + ZP_OFF / 2;
    u16* WQp = wsu + WQ_OFF / 2;
    float* BF = (float*)(wsu + BIAS_OFF / 2);
    if (i < WT_ELEMS) {
        int j = i & 7, l = (i >> 3) & 1023, s = i >> 13;
        int kb = (l >> 8) & 3;
        int co = (l & 255) ^ (kb << 1);
        float v;
        if (s < 64) {
            int t = s >> 3, ci = (s & 7) * 32 + kb * 8 + j;
            v = wh[co * 2048 + ci * 8 + t];
        } else {
            int s2 = s - 64;
            int t = s2 >> 3, ci = (s2 & 7) * 32 + kb * 8 + j;
            v = wv[co * 2048 + ci * 8 + t];
        }
        WT[i] = bfu(v);
    } else if (i < WT_ELEMS + WPW_ELEMS) {
        int i2 = i - WT_ELEMS;
        int j = i2 & 7, l = (i2 >> 3) & 1023, s = i2 >> 13;
        int kb = (l >> 8) & 3;
        int co = (l & 255) ^ (kb << 1);
        WP[i2] = bfu(wpw[co * 256 + s * 32 + kb * 8 + j]);
    } else if (i < WT_ELEMS + WPW_ELEMS + (int)(ZP_BYTES / 2)) {
        ZP[i - WT_ELEMS - WPW_ELEMS] = 0;
    } else if (i < WT_ELEMS + WPW_ELEMS + (int)(ZP_BYTES / 2) + WQ_ELEMS) {
        int i4 = i - WT_ELEMS - WPW_ELEMS - (int)(ZP_BYTES / 2);
        WQp[i4] = bfu(wqkv[i4]);
    } else {
        int i5 = i - WT_ELEMS - WPW_ELEMS - (int)(ZP_BYTES / 2) - WQ_ELEMS;
        if (i5 < 16384) {
            int lane = i5 & 63, nf = (i5 >> 6) & 3, mf = (i5 >> 8) & 3, head = i5 >> 10;
            int gg = lane >> 4, ll = lane & 15;
            #pragma unroll
            for (int r = 0; r < 4; ++r) {
                int row = 16 * mf + 4 * gg + r;
                int col = 16 * nf + ll;
                int dy = (row >> 3) - (col >> 3) + 7;
                int dx = (row & 7) - (col & 7) + 7;
                BF[i5 * 4 + r] = btab[(dy * 15 + dx) * NHEADS + head];
            }
        }
    }
}

// ---------------- halo fill for XPT: wp 0..3 & 257..263 zero, wp 256 reflect -
__global__ __launch_bounds__(256) void halo_kernel(u16* __restrict__ xp)
{
    int i = blockIdx.x * 256 + threadIdx.x;       // 2*252*12*256 total
    if (i >= 2 * 252 * 12 * 256) return;
    int ci = i & 255;
    int c12 = (i >> 8) % 12;
    int row = i / (12 * 256);                     // b*252 + h
    int wp = (c12 < 4) ? c12 : 252 + c12;
    u16 v = 0;
    if (wp == 256) v = xp[(size_t)row * XP_ROW + 254 * 256 + ci];
    xp[(size_t)row * XP_ROW + (size_t)wp * 256 + ci] = v;
}

// ---------------- Kernel B: sepconv bf16 MFMA, K=4096, B direct-to-reg -------
// grid 504 = (b,h), XCD-swizzled. 512 thr, 8 waves of 128co x 64w.
// A staged in LDS (shared x4); B fragments loaded straight from XPT into
// MFMA-layout registers (16B contiguous each) — no Bs LDS, no perms.
__global__ __launch_bounds__(512, 2) void sepconv_mfma(
    const u16* __restrict__ xpt, const u16* __restrict__ WT,
    const u16* __restrict__ ZP,
    const float* __restrict__ b_h, const float* __restrict__ b_v,
    u16* __restrict__ P)
{
    __shared__ __align__(16) u16 As[2][8192];   // [kb][co^swz][8] via WT layout

    const int bid = blockIdx.x;                 // 504 = 8*63, bijective swizzle
    const int zz = (bid & 7) * 63 + (bid >> 3);
    const int h = zz % HC, b = zz / HC;
    const int tid = threadIdx.x;
    const int lane = tid & 63, wid = tid >> 6;
    const int wr = wid >> 2, wc = wid & 3;
    const int cq = lane & 15, kb = lane >> 4;

    const u16* const xb = xpt + (size_t)(b * HC) * XP_ROW;
    const int fragb = (wc * 64 + cq + 4) * 256 + kb * 8;   // + n*16*256 per frag

    f32x4 acc[8][4];
    #pragma unroll
    for (int m = 0; m < 8; ++m)
        #pragma unroll
        for (int n = 0; n < 4; ++n) acc[m][n] = (f32x4){0.f, 0.f, 0.f, 0.f};

    u32x4 rA[2];
    u32x4 bA[4], bB[4];

#define SC_SRC(t, RP, SO)                                                      \
    if ((t) < 64) {                                                            \
        int tt = (t) >> 3;                                                     \
        int jt = h + tt - 3;                                                   \
        int jr = (jt == 252) ? 250 : jt;                                       \
        RP = (jt >= 0 && jt <= 252) ? (xpt + ((size_t)(b * HC) + jr) * XP_ROW) : ZP; \
        SO = ((t) & 7) * 32;                                                   \
    } else {                                                                   \
        int tt = ((t) - 64) >> 3;                                              \
        RP = xb + (size_t)h * XP_ROW + (tt - 3) * 256;                         \
        SO = (((t) - 64) & 7) * 32;                                            \
    }

#define SC_LOADA(t)                                                            \
    if ((t) < 128) {                                                           \
        rA[0] = *(const u32x4*)(WT + (size_t)(t) * 8192 + (size_t)tid * 8);    \
        rA[1] = *(const u32x4*)(WT + (size_t)(t) * 8192 + (size_t)(512 + tid) * 8); \
    }

#define SC_LOADB(t, BD)                                                        \
    if ((t) < 128) {                                                           \
        const u16* rp_; int so_;                                               \
        SC_SRC(t, rp_, so_)                                                    \
        _Pragma("unroll") for (int n = 0; n < 4; ++n)                          \
            BD[n] = *(const u32x4*)(rp_ + so_ + fragb + n * (16 * 256));       \
    }

#define SC_WRITEA(t, buf)                                                      \
    if ((t) < 128) {                                                           \
        *(u32x4*)&As[buf][(size_t)tid * 8] = rA[0];                            \
        *(u32x4*)&As[buf][(size_t)(512 + tid) * 8] = rA[1];                    \
    }

#define SC_MFMA(buf, BD)                                                       \
    {                                                                          \
        bf16x8 af[8];                                                          \
        _Pragma("unroll") for (int m = 0; m < 8; ++m) {                        \
            int row_ = wr * 128 + m * 16 + cq;                                 \
            af[m] = *(const bf16x8*)&As[buf][(kb * 256 + (row_ ^ (kb << 1))) * 8]; \
        }                                                                      \
        __builtin_amdgcn_s_setprio(1);                                         \
        _Pragma("unroll") for (int m = 0; m < 8; ++m) {                        \
            _Pragma("unroll") for (int n = 0; n < 4; ++n)                      \
                acc[m][n] = __builtin_amdgcn_mfma_f32_16x16x32_bf16(af[m], *(const bf16x8*)&BD[n], acc[m][n], 0, 0, 0); \
        }                                                                      \
        __builtin_amdgcn_s_setprio(0);                                         \
    }

    // ---- prologue: step 0 -> As[0] + bA; step 1 A into rA ----
    SC_LOADA(0)
    SC_LOADB(0, bA)
    SC_WRITEA(0, 0)
    SC_LOADA(1)

    #pragma unroll 1
    for (int sb = 0; sb < 128; sb += 2) {
        SC_LOADB(sb + 1, bB)
        __syncthreads();
        SC_MFMA(0, bA)
        SC_WRITEA(sb + 1, 1)       // rA holds step sb+1
        SC_LOADA(sb + 2)
        SC_LOADB(sb + 2, bA)
        __syncthreads();
        SC_MFMA(1, bB)
        SC_WRITEA(sb + 2, 0)       // rA holds step sb+2
        SC_LOADA(sb + 3)
    }

#undef SC_SRC
#undef SC_LOADA
#undef SC_LOADB
#undef SC_WRITEA
#undef SC_MFMA

    // ---- epilogue: bias + bf16 store ----
    const int rq = lane >> 4, cc = lane & 15;
    #pragma unroll
    for (int m = 0; m < 8; ++m) {
        int cgb = wr * 128 + m * 16 + rq * 4;
        float bias[4];
        #pragma unroll
        for (int rr = 0; rr < 4; ++rr) bias[rr] = b_h[cgb + rr] + b_v[cgb + rr];
        #pragma unroll
        for (int n = 0; n < 4; ++n) {
            int wg = wc * 64 + n * 16 + cc;
            if (wg < WC) {
                #pragma unroll
                for (int rr = 0; rr < 4; ++rr)
                    P[((size_t)(b * CD + cgb + rr) * HC + h) * WC + wg] = bfu(acc[m][n][rr] + bias[rr]);
            }
        }
    }
}

// ---------------- Kernel C: depthwise 8x8 conv + BN (bf16 in) -> bf16 Y ------
__global__ __launch_bounds__(256) void dwbn_kernel(
    const u16* __restrict__ P, const float* __restrict__ w_dw,
    const float* __restrict__ gamma, const float* __restrict__ beta,
    const float* __restrict__ mean, const float* __restrict__ var,
    __hip_bfloat16* __restrict__ Yb)
{
    __shared__ float ps[15][42];
    __shared__ float wd[64];
    const int bw = blockIdx.x, bh = blockIdx.y, bz = blockIdx.z;
    const int b = bz >> 8, c = bz & 255;
    const int h0 = bh * 8, w0 = bw * 32;
    const int tid = threadIdx.x;
    if (tid < 64) wd[tid] = w_dw[c * 64 + tid];
    for (int it = 0; it < 3; ++it) {
        int flat = tid + it * 256;
        if (flat < 630) {
            int row = flat / 42, col = flat % 42;
            int j = h0 - 3 + row, wcol = w0 - 3 + col;
            float v = 0.f;
            if (j >= 0 && j <= HC && wcol >= 0 && wcol <= WC) {
                int jr = (j == HC) ? (HC - 2) : j;
                int wr2 = (wcol == WC) ? (WC - 2) : wcol;
                v = bf2f(P[((size_t)(b * CD + c) * HC + jr) * WC + wr2]);
            }
            ps[row][col] = v;
        }
    }
    __syncthreads();
    const int r = tid >> 5, cc = tid & 31;
    const int h = h0 + r, w = w0 + cc;
    if (h < HC && w < WC) {
        float s = 0.f;
        #pragma unroll
        for (int u = 0; u < 8; ++u)
            #pragma unroll
            for (int v2 = 0; v2 < 8; ++v2)
                s += wd[u * 8 + v2] * ps[r + u][cc + v2];
        const float inv = gamma[c] * rsqrtf(var[c] + 1e-5f);
        Yb[((b * CD + c) * HC + h) * WC + w] = __float2bfloat16(s * inv + (beta[c] - mean[c] * inv));
    }
}

// ---------------- Kernel D: pointwise 1x1, bf16 MFMA, K=256 ------------------
// grid 504 = (b,h), XCD-swizzled. 512 thr, 8 waves of 128co x 64w. R6 skeleton.
__global__ __launch_bounds__(512, 2) void pw_mfma(
    const u16* __restrict__ Y, const u16* __restrict__ WP,
    float* __restrict__ O)
{
    __shared__ __align__(16) u16 As[2][8192];
    __shared__ __align__(16) u16 Bs[2][256 * 36];

    const int bid = blockIdx.x;
    const int zz = (bid & 7) * 63 + (bid >> 3);
    const int h = zz % HC, b = zz / HC;
    const int tid = threadIdx.x;
    const int lane = tid & 63, wid = tid >> 6;
    const int wr = wid >> 2, wc = wid & 3;
    const int cq = lane & 15, kb = lane >> 4;

    const int wl2 = (tid & 127) * 2;
    const int oc = tid >> 7;

    const u16* yb = Y + ((size_t)(b * 256 + oc * 8) * HC + h) * WC + wl2;

    const int bw0 = wl2 * 36 + oc * 8;
    const int bw1 = bw0 + 36;

    f32x4 acc[8][4];
    #pragma unroll
    for (int m = 0; m < 8; ++m)
        #pragma unroll
        for (int n = 0; n < 4; ++n) acc[m][n] = (f32x4){0.f, 0.f, 0.f, 0.f};

    u32x4 rA[2];
    u32 rB[8];

    rA[0] = *(const u32x4*)(WP + (size_t)tid * 8);
    rA[1] = *(const u32x4*)(WP + (size_t)(512 + tid) * 8);
    #pragma unroll
    for (int j = 0; j < 8; ++j)
        rB[j] = *(const u32*)(yb + (size_t)j * (HC * WC));
    *(u32x4*)&As[0][(size_t)tid * 8] = rA[0];
    *(u32x4*)&As[0][(size_t)(512 + tid) * 8] = rA[1];
    {
        union { bf16x8 v; u32 u[4]; } p0, p1;
        #pragma unroll
        for (int q = 0; q < 4; ++q) {
            p0.u[q] = __builtin_amdgcn_perm(rB[2 * q + 1], rB[2 * q], 0x05040100u);
            p1.u[q] = __builtin_amdgcn_perm(rB[2 * q + 1], rB[2 * q], 0x07060302u);
        }
        *(bf16x8*)&Bs[0][bw0] = p0.v;
        *(bf16x8*)&Bs[0][bw1] = p1.v;
    }

    #pragma unroll 1
    for (int s = 0; s < 8; ++s) {
        const int cur = s & 1;
        const int s1 = s + 1;
        if (s1 < 8) {
            rA[0] = *(const u32x4*)(WP + (size_t)s1 * 8192 + (size_t)tid * 8);
            rA[1] = *(const u32x4*)(WP + (size_t)s1 * 8192 + (size_t)(512 + tid) * 8);
            #pragma unroll
            for (int j = 0; j < 8; ++j)
                rB[j] = *(const u32*)(yb + (size_t)(s1 * 32 + j) * (HC * WC));
        }
        __syncthreads();

        {
            bf16x8 af[8], bfr[4];
            #pragma unroll
            for (int m = 0; m < 8; ++m) {
                int row = wr * 128 + m * 16 + cq;
                af[m] = *(const bf16x8*)&As[cur][(kb * 256 + (row ^ (kb << 1))) * 8];
            }
            #pragma unroll
            for (int n = 0; n < 4; ++n)
                bfr[n] = *(const bf16x8*)&Bs[cur][(wc * 64 + n * 16 + cq) * 36 + kb * 8];
            __builtin_amdgcn_s_setprio(1);
            #pragma unroll
            for (int m = 0; m < 8; ++m)
                #pragma unroll
                for (int n = 0; n < 4; ++n)
                    acc[m][n] = __builtin_amdgcn_mfma_f32_16x16x32_bf16(af[m], bfr[n], acc[m][n], 0, 0, 0);
            __builtin_amdgcn_s_setprio(0);
        }

        if (s1 < 8) {
            const int nxt = cur ^ 1;
            *(u32x4*)&As[nxt][(size_t)tid * 8] = rA[0];
            *(u32x4*)&As[nxt][(size_t)(512 + tid) * 8] = rA[1];
            union { bf16x8 v; u32 u[4]; } p0, p1;
            #pragma unroll
            for (int q = 0; q < 4; ++q) {
                p0.u[q] = __builtin_amdgcn_perm(rB[2 * q + 1], rB[2 * q], 0x05040100u);
                p1.u[q] = __builtin_amdgcn_perm(rB[2 * q + 1], rB[2 * q], 0x07060302u);
            }
            *(bf16x8*)&Bs[nxt][bw0] = p0.v;
            *(bf16x8*)&Bs[nxt][bw1] = p1.v;
        }
    }

    const int rq = lane >> 4, cc = lane & 15;
    #pragma unroll
    for (int m = 0; m < 8; ++m) {
        int cgb = wr * 128 + m * 16 + rq * 4;
        #pragma unroll
        for (int n = 0; n < 4; ++n) {
            int wg = wc * 64 + n * 16 + cc;
            if (wg < WC) {
                #pragma unroll
                for (int rr = 0; rr < 4; ++rr)
                    O[((size_t)(b * CD + cgb + rr) * HC + h) * WC + wg] = acc[m][n][rr];
            }
        }
    }
}

extern "C" void kernel_launch(void* const* d_in, const int* in_sizes, int n_in,
                              void* d_out, int out_size, void* d_ws, size_t ws_size,
                              hipStream_t stream)
{
    const float* x      = (const float*)d_in[0];
    const float* w_qkv  = (const float*)d_in[1];
    const float* bias_t = (const float*)d_in[2];
    const float* w_h    = (const float*)d_in[3];
    const float* b_h    = (const float*)d_in[4];
    const float* w_v    = (const float*)d_in[5];
    const float* b_v    = (const float*)d_in[6];
    const float* w_dw   = (const float*)d_in[7];
    const float* bn_g   = (const float*)d_in[8];
    const float* bn_b   = (const float*)d_in[9];
    const float* bn_m   = (const float*)d_in[10];
    const float* bn_v   = (const float*)d_in[11];
    const float* w_pw   = (const float*)d_in[12];
    float* out = (float*)d_out;

    u16* wsu = (u16*)d_ws;
    const u16* XPu = wsu;
    const u16* ZPu = wsu + ZP_OFF / 2;
    const u16* WTu = wsu + WT_OFF / 2;
    const u16* WPu = wsu + WPW_OFF / 2;
    const u16* WQu = wsu + WQ_OFF / 2;
    const float* BFu = (const float*)(wsu + BIAS_OFF / 2);

    // wprep -> attn(MFMA, XPT out) -> halo -> sepconv(MFMA, bf16 P) -> dwbn -> pw
    wprep_kernel<<<5984, 256, 0, stream>>>(w_h, w_v, w_pw, w_qkv, bias_t, wsu);
    attn_mfma<<<2048, 256, 0, stream>>>(x, WQu, BFu, wsu);
    halo_kernel<<<6048, 256, 0, stream>>>(wsu);
    sepconv_mfma<<<504, 512, 0, stream>>>(XPu, WTu, ZPu, b_h, b_v, (u16*)d_out);
    dwbn_kernel<<<dim3(8, 32, 512), 256, 0, stream>>>((const u16*)d_out, w_dw, bn_g, bn_b,
                                                      bn_m, bn_v, (__hip_bfloat16*)d_ws);
    pw_mfma<<<504, 512, 0, stream>>>(wsu, WPu, out);
}

// Round 13
// 711.336 us; speedup vs baseline: 1.0044x; 1.0044x over previous
//
#include <hip/hip_runtime.h>
#include <hip/hip_bf16.h>

#define HC 252
#define WC 252
#define CD 256
#define NHEADS 16

// XPT padded image, TRANSPOSED: [b][h 0..251][wp 0..263][ci 0..255], wp = w_img + 4
#define XP_W 264
#define XP_ROW (XP_W*256)            // u16 per (b,h) row: 67584
#define XP_BH  (252*XP_ROW)          // u16 per b

typedef unsigned short u16;
typedef unsigned int u32;
typedef __attribute__((ext_vector_type(4))) u16 u16x4;
typedef __attribute__((ext_vector_type(8))) short bf16x8;
typedef __attribute__((ext_vector_type(4))) float f32x4;
typedef __attribute__((ext_vector_type(4))) u32 u32x4;
typedef __attribute__((ext_vector_type(2))) u32 u32x2;

// ---- workspace layout (bytes) ----
#define XP_BYTES (2u * 2u * (unsigned)XP_BH)       // 68,124,672
#define ZP_OFF   XP_BYTES
#define ZP_BYTES 409600u
#define WT_OFF   (ZP_OFF + ZP_BYTES)
#define WT_ELEMS (128*8192)                        // [s][l(swz)][8], k=(tap,ci) order
#define WPW_OFF  (WT_OFF + (unsigned)WT_ELEMS*2u)
#define WPW_ELEMS (8*8192)
#define WQ_OFF   (WPW_OFF + (unsigned)WPW_ELEMS*2u)
#define WQ_ELEMS (768*256)
#define BIAS_OFF (WQ_OFF + (unsigned)WQ_ELEMS*2u)

__device__ __forceinline__ u16 bfu(float f) {
    __hip_bfloat16 h = __float2bfloat16(f);
    return *(reinterpret_cast<u16*>(&h));
}
__device__ __forceinline__ u32 pack2(float a, float b) {
    return (u32)bfu(a) | ((u32)bfu(b) << 16);
}
__device__ __forceinline__ float bf2f(u16 v) {
    union { u32 u; float f; } cv; cv.u = ((u32)v) << 16; return cv.f;
}

// ---------------- Kernel A: fused qkv + window attention (MFMA) --------------
// grid 2048 (XCD-swizzled), 256 threads (4 waves, 4 heads/wave).
// Head-pipelined: head hh+1's qkv MFMA block issues between QK^T and softmax
// of head hh (fills matrix pipe under softmax VALU).
__global__ __launch_bounds__(256, 2) void attn_mfma(
    const float* __restrict__ x, const u16* __restrict__ WQ,
    const float* __restrict__ BIASF, u16* __restrict__ xp)
{
    __shared__ __align__(16) char smem[73728];

    const int bid = blockIdx.x;
    const int zz = (bid & 7) * 256 + (bid >> 3);   // XCD-bijective swizzle
    const int wx = zz & 31, wy = (zz >> 5) & 31, b = zz >> 10;
    const int tid = threadIdx.x;
    const int lane = tid & 63, wid = tid >> 6;
    const int g = lane >> 4, li = lane & 15;

    // ---- stage Xwin (fp32 x -> bf16 LDS, transposed, reflect-padded) ----
    {
        int ci = tid;
        const float* srcc = x + (size_t)(b * 256 + ci) * (HC * WC);
        #pragma unroll
        for (int r = 0; r < 8; ++r) {
            int h = wy * 8 + r; if (h >= HC) h = 2 * HC - 2 - h;
            const float* src = srcc + h * WC;
            float v[8];
            if (wx == 31) {
                #pragma unroll
                for (int c = 0; c < 8; ++c) {
                    int w = 248 + c; if (w >= WC) w = 2 * WC - 2 - w;
                    v[c] = src[w];
                }
            } else {
                float4 f0 = *(const float4*)(src + wx * 8);
                float4 f1 = *(const float4*)(src + wx * 8 + 4);
                v[0]=f0.x; v[1]=f0.y; v[2]=f0.z; v[3]=f0.w;
                v[4]=f1.x; v[5]=f1.y; v[6]=f1.z; v[7]=f1.w;
            }
            #pragma unroll
            for (int c = 0; c < 8; ++c) {
                int pos = r * 8 + c;
                int byte = pos * 512 + ((ci * 2) ^ ((pos & 7) << 4));
                *(u16*)(smem + byte) = bfu(v[c]);
            }
        }
    }
    __syncthreads();

    const int WB = 32768 + wid * 10240;
    char* Qb = smem + WB;
    char* Kb = smem + WB + 2048;
    char* Vb = smem + WB + 4096;
    char* Pb = smem + WB + 6144;

    const bf16x8 zf = {0,0,0,0,0,0,0,0};

#define QKV_LOOP(ACC, HEADV)                                                  \
    for (int ks = 0; ks < 8; ++ks) {                                          \
        bf16x8 bx[4];                                                         \
        _Pragma("unroll") for (int nf = 0; nf < 4; ++nf) {                    \
            int pos = 16 * nf + li;                                           \
            int byte = pos * 512 + ((ks * 64 + 16 * g) ^ ((pos & 7) << 4));   \
            bx[nf] = *(const bf16x8*)(smem + byte);                           \
        }                                                                     \
        bf16x8 aw[3];                                                         \
        _Pragma("unroll") for (int p = 0; p < 3; ++p) {                       \
            int o = p * 256 + (HEADV) * 16 + li;                              \
            aw[p] = *(const bf16x8*)(WQ + o * 256 + ks * 32 + 8 * g);         \
        }                                                                     \
        _Pragma("unroll") for (int p = 0; p < 3; ++p) {                       \
            _Pragma("unroll") for (int nf = 0; nf < 4; ++nf)                  \
                ACC[p][nf] = __builtin_amdgcn_mfma_f32_16x16x32_bf16(aw[p], bx[nf], ACC[p][nf], 0, 0, 0); \
        }                                                                     \
    }

    f32x4 accA[3][4], accN[3][4];
    #pragma unroll
    for (int p = 0; p < 3; ++p)
        #pragma unroll
        for (int nf = 0; nf < 4; ++nf) accA[p][nf] = (f32x4){0.f,0.f,0.f,0.f};
    QKV_LOOP(accA, wid * 4)

    #pragma unroll 1
    for (int hh = 0; hh < 4; ++hh) {
        const int head = wid * 4 + hh;

        // ---- epilogue: Q/K -> [pos][d] (swz), V -> [q][d][8pos], from accA --
        #pragma unroll
        for (int p = 0; p < 3; ++p) {
            if (p < 2) {
                char* base = (p == 0) ? Qb : Kb;
                #pragma unroll
                for (int nf = 0; nf < 4; ++nf) {
                    int pos = 16 * nf + li;
                    u32 lo = pack2(accA[p][nf][0], accA[p][nf][1]);
                    u32 hi = pack2(accA[p][nf][2], accA[p][nf][3]);
                    int byte = pos * 32 + ((8 * g) ^ (((pos >> 2) & 1) << 4));
                    *(u32x2*)(base + byte) = (u32x2){lo, hi};
                }
            } else {
                #pragma unroll
                for (int nf = 0; nf < 4; ++nf) {
                    int pos = 16 * nf + li;
                    #pragma unroll
                    for (int r = 0; r < 4; ++r) {
                        int d = 4 * g + r;
                        int byte = (pos >> 3) * 256 + d * 16 + (pos & 7) * 2;
                        *(u16*)(Vb + byte) = bfu(accA[p][nf][r]);
                    }
                }
            }
        }

        // ---- QK^T (k=0..15 real, 16..31 zero) ----
        f32x4 s[4][4];
        #pragma unroll
        for (int mf = 0; mf < 4; ++mf)
            #pragma unroll
            for (int nf = 0; nf < 4; ++nf) s[mf][nf] = (f32x4){0.f,0.f,0.f,0.f};
        bf16x8 bk[4];
        #pragma unroll
        for (int nf = 0; nf < 4; ++nf) {
            int pos = 16 * nf + li;
            bk[nf] = (g < 2) ? *(const bf16x8*)(Kb + pos * 32 + ((16 * g) ^ (((pos >> 2) & 1) << 4))) : zf;
        }
        __builtin_amdgcn_s_setprio(1);
        #pragma unroll
        for (int mf = 0; mf < 4; ++mf) {
            int pos = 16 * mf + li;
            bf16x8 aq = (g < 2) ? *(const bf16x8*)(Qb + pos * 32 + ((16 * g) ^ (((pos >> 2) & 1) << 4))) : zf;
            #pragma unroll
            for (int nf = 0; nf < 4; ++nf)
                s[mf][nf] = __builtin_amdgcn_mfma_f32_16x16x32_bf16(aq, bk[nf], s[mf][nf], 0, 0, 0);
        }
        __builtin_amdgcn_s_setprio(0);

        // ---- next head's qkv (independent MFMA stream under softmax VALU) --
        if (hh < 3) {
            #pragma unroll
            for (int p = 0; p < 3; ++p)
                #pragma unroll
                for (int nf = 0; nf < 4; ++nf) accN[p][nf] = (f32x4){0.f,0.f,0.f,0.f};
            QKV_LOOP(accN, head + 1)
        }

        // ---- bias + exp + row sums ----
        f32x4 e[4][4];
        f32x4 rs[4];
        #pragma unroll
        for (int mf = 0; mf < 4; ++mf) rs[mf] = (f32x4){0.f,0.f,0.f,0.f};
        #pragma unroll
        for (int mf = 0; mf < 4; ++mf)
            #pragma unroll
            for (int nf = 0; nf < 4; ++nf) {
                f32x4 b4 = *(const f32x4*)(BIASF + (((head * 4 + mf) * 4 + nf) * 64 + lane) * 4);
                #pragma unroll
                for (int r = 0; r < 4; ++r) {
                    float ev = __expf(s[mf][nf][r] * 0.25f + b4[r]);
                    e[mf][nf][r] = ev;
                    rs[mf][r] += ev;
                }
            }
        #pragma unroll
        for (int mf = 0; mf < 4; ++mf)
            #pragma unroll
            for (int r = 0; r < 4; ++r) {
                float t = rs[mf][r];
                t += __shfl_xor(t, 1); t += __shfl_xor(t, 2);
                t += __shfl_xor(t, 4); t += __shfl_xor(t, 8);
                rs[mf][r] = t;
            }

        // ---- PV in two j-halves through the 4KB P buffer ----
        f32x4 o[4];
        #pragma unroll
        for (int mf = 0; mf < 4; ++mf) o[mf] = (f32x4){0.f,0.f,0.f,0.f};
        const bool even = !(lane & 1);
        #pragma unroll
        for (int hf = 0; hf < 2; ++hf) {
            #pragma unroll
            for (int mf = 0; mf < 4; ++mf)
                #pragma unroll
                for (int nfl = 0; nfl < 2; ++nfl) {
                    f32x4 ee = e[mf][2 * hf + nfl];
                    float p0 = __shfl_xor(ee[0], 1), p1 = __shfl_xor(ee[1], 1);
                    float p2 = __shfl_xor(ee[2], 1), p3 = __shfl_xor(ee[3], 1);
                    int jl = 16 * nfl + (li & ~1);
                    u32 w0, w1; int r0;
                    if (even) { w0 = pack2(ee[0], p0); w1 = pack2(ee[1], p1); r0 = 0; }
                    else      { w0 = pack2(p2, ee[2]); w1 = pack2(p3, ee[3]); r0 = 2; }
                    int i0 = 16 * mf + 4 * g + r0, i1 = i0 + 1;
                    *(u32*)(Pb + i0 * 64 + ((2 * jl) ^ ((i0 & 3) << 4))) = w0;
                    *(u32*)(Pb + i1 * 64 + ((2 * jl) ^ ((i1 & 3) << 4))) = w1;
                }
            bf16x8 bv = *(const bf16x8*)(Vb + (4 * hf + g) * 256 + li * 16);
            __builtin_amdgcn_s_setprio(1);
            #pragma unroll
            for (int mf = 0; mf < 4; ++mf) {
                int i = 16 * mf + li;
                bf16x8 ap = *(const bf16x8*)(Pb + i * 64 + ((16 * g) ^ ((i & 3) << 4)));
                o[mf] = __builtin_amdgcn_mfma_f32_16x16x32_bf16(ap, bv, o[mf], 0, 0, 0);
            }
            __builtin_amdgcn_s_setprio(0);
        }

        // ---- store into XPT[b][h][wp][ci] ----
        #pragma unroll
        for (int mf = 0; mf < 4; ++mf) {
            int h = wy * 8 + 2 * mf + (g >> 1);
            int wbase = wx * 8 + 4 * (g & 1);
            if (h < HC && wbase < WC) {
                size_t rowb = ((size_t)(b * HC + h)) * XP_ROW + (size_t)(head * 16 + li);
                #pragma unroll
                for (int r = 0; r < 4; ++r) {
                    float v = o[mf][r] / rs[mf][r];
                    xp[rowb + (size_t)(wbase + r + 4) * 256] = bfu(v);
                }
            }
        }

        if (hh < 3) {
            #pragma unroll
            for (int p = 0; p < 3; ++p)
                #pragma unroll
                for (int nf = 0; nf < 4; ++nf) accA[p][nf] = accN[p][nf];
        }
    }
#undef QKV_LOOP
}

// ---------------- weight prep: WT (k=(tap,ci), pre-swizzled), WP, ZP, WQ, BIASF
__global__ __launch_bounds__(256) void wprep_kernel(
    const float* __restrict__ wh, const float* __restrict__ wv,
    const float* __restrict__ wpw, const float* __restrict__ wqkv,
    const float* __restrict__ btab, u16* __restrict__ wsu)
{
    int i = blockIdx.x * 256 + threadIdx.x;
    u16* WT = wsu + WT_OFF / 2;
    u16* WP = wsu + WPW_OFF / 2;
    u16* ZP = wsu + ZP_OFF / 2;
    u16* WQp = wsu + WQ_OFF / 2;
    float* BF = (float*)(wsu + BIAS_OFF / 2);
    if (i < WT_ELEMS) {
        int j = i & 7, l = (i >> 3) & 1023, s = i >> 13;
        int kb = (l >> 8) & 3;
        int co = (l & 255) ^ (kb << 1);
        float v;
        if (s < 64) {
            int t = s >> 3, ci = (s & 7) * 32 + kb * 8 + j;
            v = wh[co * 2048 + ci * 8 + t];
        } else {
            int s2 = s - 64;
            int t = s2 >> 3, ci = (s2 & 7) * 32 + kb * 8 + j;
            v = wv[co * 2048 + ci * 8 + t];
        }
        WT[i] = bfu(v);
    } else if (i < WT_ELEMS + WPW_ELEMS) {
        int i2 = i - WT_ELEMS;
        int j = i2 & 7, l = (i2 >> 3) & 1023, s = i2 >> 13;
        int kb = (l >> 8) & 3;
        int co = (l & 255) ^ (kb << 1);
        WP[i2] = bfu(wpw[co * 256 + s * 32 + kb * 8 + j]);
    } else if (i < WT_ELEMS + WPW_ELEMS + (int)(ZP_BYTES / 2)) {
        ZP[i - WT_ELEMS - WPW_ELEMS] = 0;
    } else if (i < WT_ELEMS + WPW_ELEMS + (int)(ZP_BYTES / 2) + WQ_ELEMS) {
        int i4 = i - WT_ELEMS - WPW_ELEMS - (int)(ZP_BYTES / 2);
        WQp[i4] = bfu(wqkv[i4]);
    } else {
        int i5 = i - WT_ELEMS - WPW_ELEMS - (int)(ZP_BYTES / 2) - WQ_ELEMS;
        if (i5 < 16384) {
            int lane = i5 & 63, nf = (i5 >> 6) & 3, mf = (i5 >> 8) & 3, head = i5 >> 10;
            int gg = lane >> 4, ll = lane & 15;
            #pragma unroll
            for (int r = 0; r < 4; ++r) {
                int row = 16 * mf + 4 * gg + r;
                int col = 16 * nf + ll;
                int dy = (row >> 3) - (col >> 3) + 7;
                int dx = (row & 7) - (col & 7) + 7;
                BF[i5 * 4 + r] = btab[(dy * 15 + dx) * NHEADS + head];
            }
        }
    }
}

// ---------------- halo fill for XPT: wp 0..3 & 257..263 zero, wp 256 reflect -
__global__ __launch_bounds__(256) void halo_kernel(u16* __restrict__ xp)
{
    int i = blockIdx.x * 256 + threadIdx.x;       // 2*252*12*256 total
    if (i >= 2 * 252 * 12 * 256) return;
    int ci = i & 255;
    int c12 = (i >> 8) % 12;
    int row = i / (12 * 256);                     // b*252 + h
    int wp = (c12 < 4) ? c12 : 252 + c12;
    u16 v = 0;
    if (wp == 256) v = xp[(size_t)row * XP_ROW + 254 * 256 + ci];
    xp[(size_t)row * XP_ROW + (size_t)wp * 256 + ci] = v;
}

// ---------------- Kernel B: sepconv bf16 MFMA, K=4096, XPT B-stage (R11) -----
__global__ __launch_bounds__(512, 2) void sepconv_mfma(
    const u16* __restrict__ xpt, const u16* __restrict__ WT,
    const u16* __restrict__ ZP,
    const float* __restrict__ b_h, const float* __restrict__ b_v,
    u16* __restrict__ P)
{
    __shared__ __align__(16) u16 As[2][8192];   // [kb][co^swz][8] via WT layout
    __shared__ __align__(16) u16 Bs[2][256 * 36];

    const int bid = blockIdx.x;                 // 504 = 8*63, bijective swizzle
    const int zz = (bid & 7) * 63 + (bid >> 3);
    const int h = zz % HC, b = zz / HC;
    const int tid = threadIdx.x;
    const int lane = tid & 63, wid = tid >> 6;
    const int wr = wid >> 2, wc = wid & 3;
    const int cq = lane & 15, kb = lane >> 4;

    const int wB = tid & 255;                   // B-stage w (0..255)
    const int oc0 = tid >> 8;                   // loads ci-octets oc0, oc0+2
    const int tb = (wB + 4) * 256 + oc0 * 8;    // u16 offset within row
    const int bsw = wB * 36 + oc0 * 8;          // Bs u16 offset

    const u16* const xb = xpt + (size_t)(b * HC) * XP_ROW;

    f32x4 acc[8][4];
    #pragma unroll
    for (int m = 0; m < 8; ++m)
        #pragma unroll
        for (int n = 0; n < 4; ++n) acc[m][n] = (f32x4){0.f, 0.f, 0.f, 0.f};

    u32x4 rA[2];
    u32x4 rB0, rB1;

#define SC_SRC(t, RP, SO)                                                      \
    if ((t) < 64) {                                                            \
        int tt = (t) >> 3;                                                     \
        int jt = h + tt - 3;                                                   \
        int jr = (jt == 252) ? 250 : jt;                                       \
        RP = (jt >= 0 && jt <= 252) ? (xpt + ((size_t)(b * HC) + jr) * XP_ROW) : ZP; \
        SO = ((t) & 7) * 32;                                                   \
    } else {                                                                   \
        int tt = ((t) - 64) >> 3;                                              \
        RP = xb + (size_t)h * XP_ROW + (tt - 3) * 256;                         \
        SO = (((t) - 64) & 7) * 32;                                            \
    }

    // ---- prologue: load + write step 0 ----
    rA[0] = *(const u32x4*)(WT + (size_t)tid * 8);
    rA[1] = *(const u32x4*)(WT + (size_t)(512 + tid) * 8);
    {
        const u16* rp; int so;
        SC_SRC(0, rp, so)
        rB0 = *(const u32x4*)(rp + so + tb);
        rB1 = *(const u32x4*)(rp + so + tb + 16);
    }
    *(u32x4*)&As[0][(size_t)tid * 8] = rA[0];
    *(u32x4*)&As[0][(size_t)(512 + tid) * 8] = rA[1];
    *(u32x4*)&Bs[0][bsw] = rB0;
    *(u32x4*)&Bs[0][bsw + 16] = rB1;

    #pragma unroll 1
    for (int s = 0; s < 128; ++s) {
        const int cur = s & 1;
        const int s1 = s + 1;
        if (s1 < 128) {
            rA[0] = *(const u32x4*)(WT + (size_t)s1 * 8192 + (size_t)tid * 8);
            rA[1] = *(const u32x4*)(WT + (size_t)s1 * 8192 + (size_t)(512 + tid) * 8);
            const u16* rp; int so;
            SC_SRC(s1, rp, so)
            rB0 = *(const u32x4*)(rp + so + tb);
            rB1 = *(const u32x4*)(rp + so + tb + 16);
        }
        __syncthreads();

        {
            bf16x8 af[8], bfr[4];
            #pragma unroll
            for (int m = 0; m < 8; ++m) {
                int row = wr * 128 + m * 16 + cq;
                af[m] = *(const bf16x8*)&As[cur][(kb * 256 + (row ^ (kb << 1))) * 8];
            }
            #pragma unroll
            for (int n = 0; n < 4; ++n)
                bfr[n] = *(const bf16x8*)&Bs[cur][(wc * 64 + n * 16 + cq) * 36 + kb * 8];
            __builtin_amdgcn_s_setprio(1);
            #pragma unroll
            for (int m = 0; m < 8; ++m)
                #pragma unroll
                for (int n = 0; n < 4; ++n)
                    acc[m][n] = __builtin_amdgcn_mfma_f32_16x16x32_bf16(af[m], bfr[n], acc[m][n], 0, 0, 0);
            __builtin_amdgcn_s_setprio(0);
        }

        if (s1 < 128) {
            const int nxt = cur ^ 1;
            *(u32x4*)&As[nxt][(size_t)tid * 8] = rA[0];
            *(u32x4*)&As[nxt][(size_t)(512 + tid) * 8] = rA[1];
            *(u32x4*)&Bs[nxt][bsw] = rB0;
            *(u32x4*)&Bs[nxt][bsw + 16] = rB1;
        }
    }
#undef SC_SRC

    // ---- epilogue: bias + bf16 store ----
    const int rq = lane >> 4, cc = lane & 15;
    #pragma unroll
    for (int m = 0; m < 8; ++m) {
        int cgb = wr * 128 + m * 16 + rq * 4;
        float bias[4];
        #pragma unroll
        for (int rr = 0; rr < 4; ++rr) bias[rr] = b_h[cgb + rr] + b_v[cgb + rr];
        #pragma unroll
        for (int n = 0; n < 4; ++n) {
            int wg = wc * 64 + n * 16 + cc;
            if (wg < WC) {
                #pragma unroll
                for (int rr = 0; rr < 4; ++rr)
                    P[((size_t)(b * CD + cgb + rr) * HC + h) * WC + wg] = bfu(acc[m][n][rr] + bias[rr]);
            }
        }
    }
}

// ---------------- Kernel C: depthwise 8x8 conv + BN, 16x64 tiles -------------
// grid (4, 16, 512), 256 thr. Halo 23x71 staged in [23][73] f32 (bank-clean).
__global__ __launch_bounds__(256) void dwbn_kernel(
    const u16* __restrict__ P, const float* __restrict__ w_dw,
    const float* __restrict__ gamma, const float* __restrict__ beta,
    const float* __restrict__ mean, const float* __restrict__ var,
    __hip_bfloat16* __restrict__ Yb)
{
    __shared__ float ps[23][73];
    __shared__ float wd[64];
    const int bw = blockIdx.x, bh = blockIdx.y, bz = blockIdx.z;
    const int b = bz >> 8, c = bz & 255;
    const int h0 = bh * 16, w0 = bw * 64;
    const int tid = threadIdx.x;
    if (tid < 64) wd[tid] = w_dw[c * 64 + tid];
    for (int it = 0; it < 7; ++it) {
        int flat = tid + it * 256;
        if (flat < 23 * 71) {
            int row = flat / 71, col = flat % 71;
            int j = h0 - 3 + row, wcol = w0 - 3 + col;
            float v = 0.f;
            if (j >= 0 && j <= HC && wcol >= 0 && wcol <= WC) {
                int jr = (j == HC) ? (HC - 2) : j;
                int wr2 = (wcol == WC) ? (WC - 2) : wcol;
                v = bf2f(P[((size_t)(b * CD + c) * HC + jr) * WC + wr2]);
            }
            ps[row][col] = v;
        }
    }
    __syncthreads();
    const int r = tid >> 4;            // 0..15
    const int c0 = (tid & 15) * 4;     // 0..60
    const int h = h0 + r, w = w0 + c0;
    if (h < HC && w < WC) {
        float s0 = 0.f, s1 = 0.f, s2 = 0.f, s3 = 0.f;
        #pragma unroll
        for (int u = 0; u < 8; ++u)
            #pragma unroll
            for (int v2 = 0; v2 < 8; ++v2) {
                const float wv = wd[u * 8 + v2];
                const float* pr = &ps[r + u][c0 + v2];
                s0 += wv * pr[0]; s1 += wv * pr[1];
                s2 += wv * pr[2]; s3 += wv * pr[3];
            }
        const float inv = gamma[c] * rsqrtf(var[c] + 1e-5f);
        const float sh = beta[c] - mean[c] * inv;
        u32x2 pk;
        pk[0] = pack2(s0 * inv + sh, s1 * inv + sh);
        pk[1] = pack2(s2 * inv + sh, s3 * inv + sh);
        *(u32x2*)&Yb[((size_t)(b * CD + c) * HC + h) * WC + w] = pk;
    }
}

// ---------------- Kernel D: pointwise 1x1, bf16 MFMA, K=256 ------------------
// grid 504, 512 thr, 8 waves of 128co x 64w. Transposed epilogue via dead Bs.
__global__ __launch_bounds__(512, 2) void pw_mfma(
    const u16* __restrict__ Y, const u16* __restrict__ WP,
    float* __restrict__ O)
{
    __shared__ __align__(16) u16 As[2][8192];
    __shared__ __align__(16) u16 Bs[2][256 * 36];

    const int bid = blockIdx.x;
    const int zz = (bid & 7) * 63 + (bid >> 3);
    const int h = zz % HC, b = zz / HC;
    const int tid = threadIdx.x;
    const int lane = tid & 63, wid = tid >> 6;
    const int wr = wid >> 2, wc = wid & 3;
    const int cq = lane & 15, kb = lane >> 4;

    const int wl2 = (tid & 127) * 2;
    const int oc = tid >> 7;

    const u16* yb = Y + ((size_t)(b * 256 + oc * 8) * HC + h) * WC + wl2;

    const int bw0 = wl2 * 36 + oc * 8;
    const int bw1 = bw0 + 36;

    f32x4 acc[8][4];
    #pragma unroll
    for (int m = 0; m < 8; ++m)
        #pragma unroll
        for (int n = 0; n < 4; ++n) acc[m][n] = (f32x4){0.f, 0.f, 0.f, 0.f};

    u32x4 rA[2];
    u32 rB[8];

    rA[0] = *(const u32x4*)(WP + (size_t)tid * 8);
    rA[1] = *(const u32x4*)(WP + (size_t)(512 + tid) * 8);
    #pragma unroll
    for (int j = 0; j < 8; ++j)
        rB[j] = *(const u32*)(yb + (size_t)j * (HC * WC));
    *(u32x4*)&As[0][(size_t)tid * 8] = rA[0];
    *(u32x4*)&As[0][(size_t)(512 + tid) * 8] = rA[1];
    {
        union { bf16x8 v; u32 u[4]; } p0, p1;
        #pragma unroll
        for (int q = 0; q < 4; ++q) {
            p0.u[q] = __builtin_amdgcn_perm(rB[2 * q + 1], rB[2 * q], 0x05040100u);
            p1.u[q] = __builtin_amdgcn_perm(rB[2 * q + 1], rB[2 * q], 0x07060302u);
        }
        *(bf16x8*)&Bs[0][bw0] = p0.v;
        *(bf16x8*)&Bs[0][bw1] = p1.v;
    }

    #pragma unroll 1
    for (int s = 0; s < 8; ++s) {
        const int cur = s & 1;
        const int s1 = s + 1;
        if (s1 < 8) {
            rA[0] = *(const u32x4*)(WP + (size_t)s1 * 8192 + (size_t)tid * 8);
            rA[1] = *(const u32x4*)(WP + (size_t)s1 * 8192 + (size_t)(512 + tid) * 8);
            #pragma unroll
            for (int j = 0; j < 8; ++j)
                rB[j] = *(const u32*)(yb + (size_t)(s1 * 32 + j) * (HC * WC));
        }
        __syncthreads();

        {
            bf16x8 af[8], bfr[4];
            #pragma unroll
            for (int m = 0; m < 8; ++m) {
                int row = wr * 128 + m * 16 + cq;
                af[m] = *(const bf16x8*)&As[cur][(kb * 256 + (row ^ (kb << 1))) * 8];
            }
            #pragma unroll
            for (int n = 0; n < 4; ++n)
                bfr[n] = *(const bf16x8*)&Bs[cur][(wc * 64 + n * 16 + cq) * 36 + kb * 8];
            __builtin_amdgcn_s_setprio(1);
            #pragma unroll
            for (int m = 0; m < 8; ++m)
                #pragma unroll
                for (int n = 0; n < 4; ++n)
                    acc[m][n] = __builtin_amdgcn_mfma_f32_16x16x32_bf16(af[m], bfr[n], acc[m][n], 0, 0, 0);
            __builtin_amdgcn_s_setprio(0);
        }

        if (s1 < 8) {
            const int nxt = cur ^ 1;
            *(u32x4*)&As[nxt][(size_t)tid * 8] = rA[0];
            *(u32x4*)&As[nxt][(size_t)(512 + tid) * 8] = rA[1];
            union { bf16x8 v; u32 u[4]; } p0, p1;
            #pragma unroll
            for (int q = 0; q < 4; ++q) {
                p0.u[q] = __builtin_amdgcn_perm(rB[2 * q + 1], rB[2 * q], 0x05040100u);
                p1.u[q] = __builtin_amdgcn_perm(rB[2 * q + 1], rB[2 * q], 0x07060302u);
            }
            *(bf16x8*)&Bs[nxt][bw0] = p0.v;
            *(bf16x8*)&Bs[nxt][bw1] = p1.v;
        }
    }

    // ---- transposed epilogue: acc -> per-wave slab in dead Bs -> dwordx4 ----
    __syncthreads();                               // all MFMA reads of Bs done
    float* tsl = (float*)&Bs[0][0] + wid * (16 * 68);
    const int rq = lane >> 4;
    const int r2 = lane >> 2;                      // 0..15 (co_local)
    const int wq = (lane & 3) * 16;                // w_local base
    #pragma unroll
    for (int m = 0; m < 8; ++m) {
        #pragma unroll
        for (int n = 0; n < 4; ++n)
            #pragma unroll
            for (int rr = 0; rr < 4; ++rr)
                tsl[(rq * 4 + rr) * 68 + n * 16 + cq] = acc[m][n][rr];
        const int co = wr * 128 + m * 16 + r2;
        float* orow = O + ((size_t)(b * CD + co) * HC + h) * WC + wc * 64;
        #pragma unroll
        for (int q = 0; q < 4; ++q) {
            int wl = wq + 4 * q;
            if (wc * 64 + wl < WC) {
                f32x4 v4 = *(const f32x4*)&tsl[r2 * 68 + wl];
                *(f32x4*)&orow[wl] = v4;
            }
        }
    }
}

extern "C" void kernel_launch(void* const* d_in, const int* in_sizes, int n_in,
                              void* d_out, int out_size, void* d_ws, size_t ws_size,
                              hipStream_t stream)
{
    const float* x      = (const float*)d_in[0];
    const float* w_qkv  = (const float*)d_in[1];
    const float* bias_t = (const float*)d_in[2];
    const float* w_h    = (const float*)d_in[3];
    const float* b_h    = (const float*)d_in[4];
    const float* w_v    = (const float*)d_in[5];
    const float* b_v    = (const float*)d_in[6];
    const float* w_dw   = (const float*)d_in[7];
    const float* bn_g   = (const float*)d_in[8];
    const float* bn_b   = (const float*)d_in[9];
    const float* bn_m   = (const float*)d_in[10];
    const float* bn_v   = (const float*)d_in[11];
    const float* w_pw   = (const float*)d_in[12];
    float* out = (float*)d_out;

    u16* wsu = (u16*)d_ws;
    const u16* XPu = wsu;
    const u16* ZPu = wsu + ZP_OFF / 2;
    const u16* WTu = wsu + WT_OFF / 2;
    const u16* WPu = wsu + WPW_OFF / 2;
    const u16* WQu = wsu + WQ_OFF / 2;
    const float* BFu = (const float*)(wsu + BIAS_OFF / 2);

    // wprep -> attn(MFMA, XPT out) -> halo -> sepconv(MFMA, bf16 P) -> dwbn -> pw
    wprep_kernel<<<5984, 256, 0, stream>>>(w_h, w_v, w_pw, w_qkv, bias_t, wsu);
    attn_mfma<<<2048, 256, 0, stream>>>(x, WQu, BFu, wsu);
    halo_kernel<<<6048, 256, 0, stream>>>(wsu);
    sepconv_mfma<<<504, 512, 0, stream>>>(XPu, WTu, ZPu, b_h, b_v, (u16*)d_out);
    dwbn_kernel<<<dim3(4, 16, 512), 256, 0, stream>>>((const u16*)d_out, w_dw, bn_g, bn_b,
                                                      bn_m, bn_v, (__hip_bfloat16*)d_ws);
    pw_mfma<<<504, 512, 0, stream>>>(wsu, WPu, out);
}

// Round 14
// 631.042 us; speedup vs baseline: 1.1322x; 1.1272x over previous
//
#include <hip/hip_runtime.h>
#include <hip/hip_bf16.h>

#define HC 252
#define WC 252
#define CD 256
#define NHEADS 16

// XPT padded image, TRANSPOSED: [b][h 0..251][wp 0..263][ci 0..255], wp = w_img + 4
#define XP_W 264
#define XP_ROW (XP_W*256)            // u16 per (b,h) row: 67584
#define XP_BH  (252*XP_ROW)          // u16 per b

typedef unsigned short u16;
typedef unsigned int u32;
typedef __attribute__((ext_vector_type(8))) short bf16x8;
typedef __attribute__((ext_vector_type(4))) float f32x4;
typedef __attribute__((ext_vector_type(4))) u32 u32x4;
typedef __attribute__((ext_vector_type(2))) u32 u32x2;

// ---- workspace layout (bytes) ----
#define XP_BYTES (2u * 2u * (unsigned)XP_BH)       // 68,124,672
#define ZP_OFF   XP_BYTES
#define ZP_BYTES 409600u
#define WT_OFF   (ZP_OFF + ZP_BYTES)
#define WT_ELEMS (128*8192)                        // [s][l(swz)][8], k=(tap,ci) order
#define WPW_OFF  (WT_OFF + (unsigned)WT_ELEMS*2u)
#define WPW_ELEMS (8*8192)
#define WQ_OFF   (WPW_OFF + (unsigned)WPW_ELEMS*2u)
#define WQ_ELEMS (768*256)
#define BIAS_OFF (WQ_OFF + (unsigned)WQ_ELEMS*2u)

__device__ __forceinline__ u16 bfu(float f) {
    __hip_bfloat16 h = __float2bfloat16(f);
    return *(reinterpret_cast<u16*>(&h));
}
__device__ __forceinline__ u32 pack2(float a, float b) {
    return (u32)bfu(a) | ((u32)bfu(b) << 16);
}
__device__ __forceinline__ float bf2f(u16 v) {
    union { u32 u; float f; } cv; cv.u = ((u32)v) << 16; return cv.f;
}

// ---------------- Kernel A: fused qkv + window attention (MFMA) --------------
// grid 2048 (XCD-swizzled), 256 threads (4 waves, 4 heads/wave, sequential).
__global__ __launch_bounds__(256, 2) void attn_mfma(
    const float* __restrict__ x, const u16* __restrict__ WQ,
    const float* __restrict__ BIASF, u16* __restrict__ xp)
{
    __shared__ __align__(16) char smem[73728];

    const int bid = blockIdx.x;
    const int zz = (bid & 7) * 256 + (bid >> 3);   // XCD-bijective swizzle
    const int wx = zz & 31, wy = (zz >> 5) & 31, b = zz >> 10;
    const int tid = threadIdx.x;
    const int lane = tid & 63, wid = tid >> 6;
    const int g = lane >> 4, li = lane & 15;

    // ---- stage Xwin (fp32 x -> bf16 LDS, transposed, reflect-padded) ----
    {
        int ci = tid;
        const float* srcc = x + (size_t)(b * 256 + ci) * (HC * WC);
        #pragma unroll
        for (int r = 0; r < 8; ++r) {
            int h = wy * 8 + r; if (h >= HC) h = 2 * HC - 2 - h;
            const float* src = srcc + h * WC;
            float v[8];
            if (wx == 31) {
                #pragma unroll
                for (int c = 0; c < 8; ++c) {
                    int w = 248 + c; if (w >= WC) w = 2 * WC - 2 - w;
                    v[c] = src[w];
                }
            } else {
                float4 f0 = *(const float4*)(src + wx * 8);
                float4 f1 = *(const float4*)(src + wx * 8 + 4);
                v[0]=f0.x; v[1]=f0.y; v[2]=f0.z; v[3]=f0.w;
                v[4]=f1.x; v[5]=f1.y; v[6]=f1.z; v[7]=f1.w;
            }
            #pragma unroll
            for (int c = 0; c < 8; ++c) {
                int pos = r * 8 + c;
                int byte = pos * 512 + ((ci * 2) ^ ((pos & 7) << 4));
                *(u16*)(smem + byte) = bfu(v[c]);
            }
        }
    }
    __syncthreads();

    const int WB = 32768 + wid * 10240;
    char* Qb = smem + WB;
    char* Kb = smem + WB + 2048;
    char* Vb = smem + WB + 4096;
    char* Pb = smem + WB + 6144;

    const bf16x8 zf = {0,0,0,0,0,0,0,0};

    #pragma unroll 1
    for (int hh = 0; hh < 4; ++hh) {
        const int head = wid * 4 + hh;

        f32x4 acc[3][4];
        #pragma unroll
        for (int p = 0; p < 3; ++p)
            #pragma unroll
            for (int nf = 0; nf < 4; ++nf) acc[p][nf] = (f32x4){0.f,0.f,0.f,0.f};

        for (int ks = 0; ks < 8; ++ks) {
            bf16x8 bx[4];
            #pragma unroll
            for (int nf = 0; nf < 4; ++nf) {
                int pos = 16 * nf + li;
                int byte = pos * 512 + ((ks * 64 + 16 * g) ^ ((pos & 7) << 4));
                bx[nf] = *(const bf16x8*)(smem + byte);
            }
            bf16x8 aw[3];
            #pragma unroll
            for (int p = 0; p < 3; ++p) {
                int o = p * 256 + head * 16 + li;
                aw[p] = *(const bf16x8*)(WQ + o * 256 + ks * 32 + 8 * g);
            }
            __builtin_amdgcn_s_setprio(1);
            #pragma unroll
            for (int p = 0; p < 3; ++p)
                #pragma unroll
                for (int nf = 0; nf < 4; ++nf)
                    acc[p][nf] = __builtin_amdgcn_mfma_f32_16x16x32_bf16(aw[p], bx[nf], acc[p][nf], 0, 0, 0);
            __builtin_amdgcn_s_setprio(0);
        }

        #pragma unroll
        for (int p = 0; p < 3; ++p) {
            if (p < 2) {
                char* base = (p == 0) ? Qb : Kb;
                #pragma unroll
                for (int nf = 0; nf < 4; ++nf) {
                    int pos = 16 * nf + li;
                    u32 lo = pack2(acc[p][nf][0], acc[p][nf][1]);
                    u32 hi = pack2(acc[p][nf][2], acc[p][nf][3]);
                    int byte = pos * 32 + ((8 * g) ^ (((pos >> 2) & 1) << 4));
                    *(u32x2*)(base + byte) = (u32x2){lo, hi};
                }
            } else {
                #pragma unroll
                for (int nf = 0; nf < 4; ++nf) {
                    int pos = 16 * nf + li;
                    #pragma unroll
                    for (int r = 0; r < 4; ++r) {
                        int d = 4 * g + r;
                        int byte = (pos >> 3) * 256 + d * 16 + (pos & 7) * 2;
                        *(u16*)(Vb + byte) = bfu(acc[p][nf][r]);
                    }
                }
            }
        }

        f32x4 s[4][4];
        #pragma unroll
        for (int mf = 0; mf < 4; ++mf)
            #pragma unroll
            for (int nf = 0; nf < 4; ++nf) s[mf][nf] = (f32x4){0.f,0.f,0.f,0.f};
        bf16x8 bk[4];
        #pragma unroll
        for (int nf = 0; nf < 4; ++nf) {
            int pos = 16 * nf + li;
            bk[nf] = (g < 2) ? *(const bf16x8*)(Kb + pos * 32 + ((16 * g) ^ (((pos >> 2) & 1) << 4))) : zf;
        }
        __builtin_amdgcn_s_setprio(1);
        #pragma unroll
        for (int mf = 0; mf < 4; ++mf) {
            int pos = 16 * mf + li;
            bf16x8 aq = (g < 2) ? *(const bf16x8*)(Qb + pos * 32 + ((16 * g) ^ (((pos >> 2) & 1) << 4))) : zf;
            #pragma unroll
            for (int nf = 0; nf < 4; ++nf)
                s[mf][nf] = __builtin_amdgcn_mfma_f32_16x16x32_bf16(aq, bk[nf], s[mf][nf], 0, 0, 0);
        }
        __builtin_amdgcn_s_setprio(0);

        f32x4 e[4][4];
        f32x4 rs[4];
        #pragma unroll
        for (int mf = 0; mf < 4; ++mf) rs[mf] = (f32x4){0.f,0.f,0.f,0.f};
        #pragma unroll
        for (int mf = 0; mf < 4; ++mf)
            #pragma unroll
            for (int nf = 0; nf < 4; ++nf) {
                f32x4 b4 = *(const f32x4*)(BIASF + (((head * 4 + mf) * 4 + nf) * 64 + lane) * 4);
                #pragma unroll
                for (int r = 0; r < 4; ++r) {
                    float ev = __expf(s[mf][nf][r] * 0.25f + b4[r]);
                    e[mf][nf][r] = ev;
                    rs[mf][r] += ev;
                }
            }
        #pragma unroll
        for (int mf = 0; mf < 4; ++mf)
            #pragma unroll
            for (int r = 0; r < 4; ++r) {
                float t = rs[mf][r];
                t += __shfl_xor(t, 1); t += __shfl_xor(t, 2);
                t += __shfl_xor(t, 4); t += __shfl_xor(t, 8);
                rs[mf][r] = t;
            }

        f32x4 o[4];
        #pragma unroll
        for (int mf = 0; mf < 4; ++mf) o[mf] = (f32x4){0.f,0.f,0.f,0.f};
        const bool even = !(lane & 1);
        #pragma unroll
        for (int hf = 0; hf < 2; ++hf) {
            #pragma unroll
            for (int mf = 0; mf < 4; ++mf)
                #pragma unroll
                for (int nfl = 0; nfl < 2; ++nfl) {
                    f32x4 ee = e[mf][2 * hf + nfl];
                    float p0 = __shfl_xor(ee[0], 1), p1 = __shfl_xor(ee[1], 1);
                    float p2 = __shfl_xor(ee[2], 1), p3 = __shfl_xor(ee[3], 1);
                    int jl = 16 * nfl + (li & ~1);
                    u32 w0, w1; int r0;
                    if (even) { w0 = pack2(ee[0], p0); w1 = pack2(ee[1], p1); r0 = 0; }
                    else      { w0 = pack2(p2, ee[2]); w1 = pack2(p3, ee[3]); r0 = 2; }
                    int i0 = 16 * mf + 4 * g + r0, i1 = i0 + 1;
                    *(u32*)(Pb + i0 * 64 + ((2 * jl) ^ ((i0 & 3) << 4))) = w0;
                    *(u32*)(Pb + i1 * 64 + ((2 * jl) ^ ((i1 & 3) << 4))) = w1;
                }
            bf16x8 bv = *(const bf16x8*)(Vb + (4 * hf + g) * 256 + li * 16);
            __builtin_amdgcn_s_setprio(1);
            #pragma unroll
            for (int mf = 0; mf < 4; ++mf) {
                int i = 16 * mf + li;
                bf16x8 ap = *(const bf16x8*)(Pb + i * 64 + ((16 * g) ^ ((i & 3) << 4)));
                o[mf] = __builtin_amdgcn_mfma_f32_16x16x32_bf16(ap, bv, o[mf], 0, 0, 0);
            }
            __builtin_amdgcn_s_setprio(0);
        }

        // ---- store into XPT[b][h][wp][ci] ----
        #pragma unroll
        for (int mf = 0; mf < 4; ++mf) {
            int h = wy * 8 + 2 * mf + (g >> 1);
            int wbase = wx * 8 + 4 * (g & 1);
            if (h < HC && wbase < WC) {
                size_t rowb = ((size_t)(b * HC + h)) * XP_ROW + (size_t)(head * 16 + li);
                #pragma unroll
                for (int r = 0; r < 4; ++r) {
                    float v = o[mf][r] / rs[mf][r];
                    xp[rowb + (size_t)(wbase + r + 4) * 256] = bfu(v);
                }
            }
        }
    }
}

// ---------------- weight prep: WT (k=(tap,ci), pre-swizzled), WP, ZP, WQ, BIASF
__global__ __launch_bounds__(256) void wprep_kernel(
    const float* __restrict__ wh, const float* __restrict__ wv,
    const float* __restrict__ wpw, const float* __restrict__ wqkv,
    const float* __restrict__ btab, u16* __restrict__ wsu)
{
    int i = blockIdx.x * 256 + threadIdx.x;
    u16* WT = wsu + WT_OFF / 2;
    u16* WP = wsu + WPW_OFF / 2;
    u16* ZP = wsu + ZP_OFF / 2;
    u16* WQp = wsu + WQ_OFF / 2;
    float* BF = (float*)(wsu + BIAS_OFF / 2);
    if (i < WT_ELEMS) {
        int j = i & 7, l = (i >> 3) & 1023, s = i >> 13;
        int kb = (l >> 8) & 3;
        int co = (l & 255) ^ (kb << 1);
        float v;
        if (s < 64) {
            int t = s >> 3, ci = (s & 7) * 32 + kb * 8 + j;
            v = wh[co * 2048 + ci * 8 + t];
        } else {
            int s2 = s - 64;
            int t = s2 >> 3, ci = (s2 & 7) * 32 + kb * 8 + j;
            v = wv[co * 2048 + ci * 8 + t];
        }
        WT[i] = bfu(v);
    } else if (i < WT_ELEMS + WPW_ELEMS) {
        int i2 = i - WT_ELEMS;
        int j = i2 & 7, l = (i2 >> 3) & 1023, s = i2 >> 13;
        int kb = (l >> 8) & 3;
        int co = (l & 255) ^ (kb << 1);
        WP[i2] = bfu(wpw[co * 256 + s * 32 + kb * 8 + j]);
    } else if (i < WT_ELEMS + WPW_ELEMS + (int)(ZP_BYTES / 2)) {
        ZP[i - WT_ELEMS - WPW_ELEMS] = 0;
    } else if (i < WT_ELEMS + WPW_ELEMS + (int)(ZP_BYTES / 2) + WQ_ELEMS) {
        int i4 = i - WT_ELEMS - WPW_ELEMS - (int)(ZP_BYTES / 2);
        WQp[i4] = bfu(wqkv[i4]);
    } else {
        int i5 = i - WT_ELEMS - WPW_ELEMS - (int)(ZP_BYTES / 2) - WQ_ELEMS;
        if (i5 < 16384) {
            int lane = i5 & 63, nf = (i5 >> 6) & 3, mf = (i5 >> 8) & 3, head = i5 >> 10;
            int gg = lane >> 4, ll = lane & 15;
            #pragma unroll
            for (int r = 0; r < 4; ++r) {
                int row = 16 * mf + 4 * gg + r;
                int col = 16 * nf + ll;
                int dy = (row >> 3) - (col >> 3) + 7;
                int dx = (row & 7) - (col & 7) + 7;
                BF[i5 * 4 + r] = btab[(dy * 15 + dx) * NHEADS + head];
            }
        }
    }
}

// ---------------- halo fill for XPT: wp 0..3 & 257..263 zero, wp 256 reflect -
__global__ __launch_bounds__(256) void halo_kernel(u16* __restrict__ xp)
{
    int i = blockIdx.x * 256 + threadIdx.x;       // 2*252*12*256 total
    if (i >= 2 * 252 * 12 * 256) return;
    int ci = i & 255;
    int c12 = (i >> 8) % 12;
    int row = i / (12 * 256);                     // b*252 + h
    int wp = (c12 < 4) ? c12 : 252 + c12;
    u16 v = 0;
    if (wp == 256) v = xp[(size_t)row * XP_ROW + 254 * 256 + ci];
    xp[(size_t)row * XP_ROW + (size_t)wp * 256 + ci] = v;
}

// ---------------- Kernel B: sepconv bf16 MFMA, K=4096, XPT B-stage (R11) -----
__global__ __launch_bounds__(512, 2) void sepconv_mfma(
    const u16* __restrict__ xpt, const u16* __restrict__ WT,
    const u16* __restrict__ ZP,
    const float* __restrict__ b_h, const float* __restrict__ b_v,
    u16* __restrict__ P)
{
    __shared__ __align__(16) u16 As[2][8192];   // [kb][co^swz][8] via WT layout
    __shared__ __align__(16) u16 Bs[2][256 * 36];

    const int bid = blockIdx.x;                 // 504 = 8*63, bijective swizzle
    const int zz = (bid & 7) * 63 + (bid >> 3);
    const int h = zz % HC, b = zz / HC;
    const int tid = threadIdx.x;
    const int lane = tid & 63, wid = tid >> 6;
    const int wr = wid >> 2, wc = wid & 3;
    const int cq = lane & 15, kb = lane >> 4;

    const int wB = tid & 255;                   // B-stage w (0..255)
    const int oc0 = tid >> 8;                   // loads ci-octets oc0, oc0+2
    const int tb = (wB + 4) * 256 + oc0 * 8;    // u16 offset within row
    const int bsw = wB * 36 + oc0 * 8;          // Bs u16 offset

    const u16* const xb = xpt + (size_t)(b * HC) * XP_ROW;

    f32x4 acc[8][4];
    #pragma unroll
    for (int m = 0; m < 8; ++m)
        #pragma unroll
        for (int n = 0; n < 4; ++n) acc[m][n] = (f32x4){0.f, 0.f, 0.f, 0.f};

    u32x4 rA[2];
    u32x4 rB0, rB1;

#define SC_SRC(t, RP, SO)                                                      \
    if ((t) < 64) {                                                            \
        int tt = (t) >> 3;                                                     \
        int jt = h + tt - 3;                                                   \
        int jr = (jt == 252) ? 250 : jt;                                       \
        RP = (jt >= 0 && jt <= 252) ? (xpt + ((size_t)(b * HC) + jr) * XP_ROW) : ZP; \
        SO = ((t) & 7) * 32;                                                   \
    } else {                                                                   \
        int tt = ((t) - 64) >> 3;                                              \
        RP = xb + (size_t)h * XP_ROW + (tt - 3) * 256;                         \
        SO = (((t) - 64) & 7) * 32;                                            \
    }

    // ---- prologue: load + write step 0 ----
    rA[0] = *(const u32x4*)(WT + (size_t)tid * 8);
    rA[1] = *(const u32x4*)(WT + (size_t)(512 + tid) * 8);
    {
        const u16* rp; int so;
        SC_SRC(0, rp, so)
        rB0 = *(const u32x4*)(rp + so + tb);
        rB1 = *(const u32x4*)(rp + so + tb + 16);
    }
    *(u32x4*)&As[0][(size_t)tid * 8] = rA[0];
    *(u32x4*)&As[0][(size_t)(512 + tid) * 8] = rA[1];
    *(u32x4*)&Bs[0][bsw] = rB0;
    *(u32x4*)&Bs[0][bsw + 16] = rB1;

    #pragma unroll 1
    for (int s = 0; s < 128; ++s) {
        const int cur = s & 1;
        const int s1 = s + 1;
        if (s1 < 128) {
            rA[0] = *(const u32x4*)(WT + (size_t)s1 * 8192 + (size_t)tid * 8);
            rA[1] = *(const u32x4*)(WT + (size_t)s1 * 8192 + (size_t)(512 + tid) * 8);
            const u16* rp; int so;
            SC_SRC(s1, rp, so)
            rB0 = *(const u32x4*)(rp + so + tb);
            rB1 = *(const u32x4*)(rp + so + tb + 16);
        }
        __syncthreads();

        {
            bf16x8 af[8], bfr[4];
            #pragma unroll
            for (int m = 0; m < 8; ++m) {
                int row = wr * 128 + m * 16 + cq;
                af[m] = *(const bf16x8*)&As[cur][(kb * 256 + (row ^ (kb << 1))) * 8];
            }
            #pragma unroll
            for (int n = 0; n < 4; ++n)
                bfr[n] = *(const bf16x8*)&Bs[cur][(wc * 64 + n * 16 + cq) * 36 + kb * 8];
            __builtin_amdgcn_s_setprio(1);
            #pragma unroll
            for (int m = 0; m < 8; ++m)
                #pragma unroll
                for (int n = 0; n < 4; ++n)
                    acc[m][n] = __builtin_amdgcn_mfma_f32_16x16x32_bf16(af[m], bfr[n], acc[m][n], 0, 0, 0);
            __builtin_amdgcn_s_setprio(0);
        }

        if (s1 < 128) {
            const int nxt = cur ^ 1;
            *(u32x4*)&As[nxt][(size_t)tid * 8] = rA[0];
            *(u32x4*)&As[nxt][(size_t)(512 + tid) * 8] = rA[1];
            *(u32x4*)&Bs[nxt][bsw] = rB0;
            *(u32x4*)&Bs[nxt][bsw + 16] = rB1;
        }
    }
#undef SC_SRC

    // ---- epilogue: bias + bf16 store ----
    const int rq = lane >> 4, cc = lane & 15;
    #pragma unroll
    for (int m = 0; m < 8; ++m) {
        int cgb = wr * 128 + m * 16 + rq * 4;
        float bias[4];
        #pragma unroll
        for (int rr = 0; rr < 4; ++rr) bias[rr] = b_h[cgb + rr] + b_v[cgb + rr];
        #pragma unroll
        for (int n = 0; n < 4; ++n) {
            int wg = wc * 64 + n * 16 + cc;
            if (wg < WC) {
                #pragma unroll
                for (int rr = 0; rr < 4; ++rr)
                    P[((size_t)(b * CD + cgb + rr) * HC + h) * WC + wg] = bfu(acc[m][n][rr] + bias[rr]);
            }
        }
    }
}

// ---------------- Kernel C: depthwise 8x8 conv + BN, 16x64 tiles -------------
__global__ __launch_bounds__(256) void dwbn_kernel(
    const u16* __restrict__ P, const float* __restrict__ w_dw,
    const float* __restrict__ gamma, const float* __restrict__ beta,
    const float* __restrict__ mean, const float* __restrict__ var,
    __hip_bfloat16* __restrict__ Yb)
{
    __shared__ float ps[23][73];
    __shared__ float wd[64];
    const int bw = blockIdx.x, bh = blockIdx.y, bz = blockIdx.z;
    const int b = bz >> 8, c = bz & 255;
    const int h0 = bh * 16, w0 = bw * 64;
    const int tid = threadIdx.x;
    if (tid < 64) wd[tid] = w_dw[c * 64 + tid];
    for (int it = 0; it < 7; ++it) {
        int flat = tid + it * 256;
        if (flat < 23 * 71) {
            int row = flat / 71, col = flat % 71;
            int j = h0 - 3 + row, wcol = w0 - 3 + col;
            float v = 0.f;
            if (j >= 0 && j <= HC && wcol >= 0 && wcol <= WC) {
                int jr = (j == HC) ? (HC - 2) : j;
                int wr2 = (wcol == WC) ? (WC - 2) : wcol;
                v = bf2f(P[((size_t)(b * CD + c) * HC + jr) * WC + wr2]);
            }
            ps[row][col] = v;
        }
    }
    __syncthreads();
    const int r = tid >> 4;            // 0..15
    const int c0 = (tid & 15) * 4;     // 0..60
    const int h = h0 + r, w = w0 + c0;
    if (h < HC && w < WC) {
        float s0 = 0.f, s1 = 0.f, s2 = 0.f, s3 = 0.f;
        #pragma unroll
        for (int u = 0; u < 8; ++u)
            #pragma unroll
            for (int v2 = 0; v2 < 8; ++v2) {
                const float wv = wd[u * 8 + v2];
                const float* pr = &ps[r + u][c0 + v2];
                s0 += wv * pr[0]; s1 += wv * pr[1];
                s2 += wv * pr[2]; s3 += wv * pr[3];
            }
        const float inv = gamma[c] * rsqrtf(var[c] + 1e-5f);
        const float sh = beta[c] - mean[c] * inv;
        u32x2 pk;
        pk[0] = pack2(s0 * inv + sh, s1 * inv + sh);
        pk[1] = pack2(s2 * inv + sh, s3 * inv + sh);
        *(u32x2*)&Yb[((size_t)(b * CD + c) * HC + h) * WC + w] = pk;
    }
}

// ---------------- Kernel D: pointwise 1x1, bf16 MFMA, K=256 ------------------
// grid 504, 512 thr, 8 waves of 128co x 64w. Transposed epilogue via dead Bs.
__global__ __launch_bounds__(512, 2) void pw_mfma(
    const u16* __restrict__ Y, const u16* __restrict__ WP,
    float* __restrict__ O)
{
    __shared__ __align__(16) u16 As[2][8192];
    __shared__ __align__(16) u16 Bs[2][256 * 36];

    const int bid = blockIdx.x;
    const int zz = (bid & 7) * 63 + (bid >> 3);
    const int h = zz % HC, b = zz / HC;
    const int tid = threadIdx.x;
    const int lane = tid & 63, wid = tid >> 6;
    const int wr = wid >> 2, wc = wid & 3;
    const int cq = lane & 15, kb = lane >> 4;

    const int wl2 = (tid & 127) * 2;
    const int oc = tid >> 7;

    const u16* yb = Y + ((size_t)(b * 256 + oc * 8) * HC + h) * WC + wl2;

    const int bw0 = wl2 * 36 + oc * 8;
    const int bw1 = bw0 + 36;

    f32x4 acc[8][4];
    #pragma unroll
    for (int m = 0; m < 8; ++m)
        #pragma unroll
        for (int n = 0; n < 4; ++n) acc[m][n] = (f32x4){0.f, 0.f, 0.f, 0.f};

    u32x4 rA[2];
    u32 rB[8];

    rA[0] = *(const u32x4*)(WP + (size_t)tid * 8);
    rA[1] = *(const u32x4*)(WP + (size_t)(512 + tid) * 8);
    #pragma unroll
    for (int j = 0; j < 8; ++j)
        rB[j] = *(const u32*)(yb + (size_t)j * (HC * WC));
    *(u32x4*)&As[0][(size_t)tid * 8] = rA[0];
    *(u32x4*)&As[0][(size_t)(512 + tid) * 8] = rA[1];
    {
        union { bf16x8 v; u32 u[4]; } p0, p1;
        #pragma unroll
        for (int q = 0; q < 4; ++q) {
            p0.u[q] = __builtin_amdgcn_perm(rB[2 * q + 1], rB[2 * q], 0x05040100u);
            p1.u[q] = __builtin_amdgcn_perm(rB[2 * q + 1], rB[2 * q], 0x07060302u);
        }
        *(bf16x8*)&Bs[0][bw0] = p0.v;
        *(bf16x8*)&Bs[0][bw1] = p1.v;
    }

    #pragma unroll 1
    for (int s = 0; s < 8; ++s) {
        const int cur = s & 1;
        const int s1 = s + 1;
        if (s1 < 8) {
            rA[0] = *(const u32x4*)(WP + (size_t)s1 * 8192 + (size_t)tid * 8);
            rA[1] = *(const u32x4*)(WP + (size_t)s1 * 8192 + (size_t)(512 + tid) * 8);
            #pragma unroll
            for (int j = 0; j < 8; ++j)
                rB[j] = *(const u32*)(yb + (size_t)(s1 * 32 + j) * (HC * WC));
        }
        __syncthreads();

        {
            bf16x8 af[8], bfr[4];
            #pragma unroll
            for (int m = 0; m < 8; ++m) {
                int row = wr * 128 + m * 16 + cq;
                af[m] = *(const bf16x8*)&As[cur][(kb * 256 + (row ^ (kb << 1))) * 8];
            }
            #pragma unroll
            for (int n = 0; n < 4; ++n)
                bfr[n] = *(const bf16x8*)&Bs[cur][(wc * 64 + n * 16 + cq) * 36 + kb * 8];
            __builtin_amdgcn_s_setprio(1);
            #pragma unroll
            for (int m = 0; m < 8; ++m)
                #pragma unroll
                for (int n = 0; n < 4; ++n)
                    acc[m][n] = __builtin_amdgcn_mfma_f32_16x16x32_bf16(af[m], bfr[n], acc[m][n], 0, 0, 0);
            __builtin_amdgcn_s_setprio(0);
        }

        if (s1 < 8) {
            const int nxt = cur ^ 1;
            *(u32x4*)&As[nxt][(size_t)tid * 8] = rA[0];
            *(u32x4*)&As[nxt][(size_t)(512 + tid) * 8] = rA[1];
            union { bf16x8 v; u32 u[4]; } p0, p1;
            #pragma unroll
            for (int q = 0; q < 4; ++q) {
                p0.u[q] = __builtin_amdgcn_perm(rB[2 * q + 1], rB[2 * q], 0x05040100u);
                p1.u[q] = __builtin_amdgcn_perm(rB[2 * q + 1], rB[2 * q], 0x07060302u);
            }
            *(bf16x8*)&Bs[nxt][bw0] = p0.v;
            *(bf16x8*)&Bs[nxt][bw1] = p1.v;
        }
    }

    // ---- transposed epilogue: acc -> per-wave slab in dead Bs -> dwordx4 ----
    __syncthreads();                               // all MFMA reads of Bs done
    float* tsl = (float*)&Bs[0][0] + wid * (16 * 68);
    const int rq = lane >> 4;
    const int r2 = lane >> 2;                      // 0..15 (co_local)
    const int wq = (lane & 3) * 16;                // w_local base
    #pragma unroll
    for (int m = 0; m < 8; ++m) {
        #pragma unroll
        for (int n = 0; n < 4; ++n)
            #pragma unroll
            for (int rr = 0; rr < 4; ++rr)
                tsl[(rq * 4 + rr) * 68 + n * 16 + cq] = acc[m][n][rr];
        const int co = wr * 128 + m * 16 + r2;
        float* orow = O + ((size_t)(b * CD + co) * HC + h) * WC + wc * 64;
        #pragma unroll
        for (int q = 0; q < 4; ++q) {
            int wl = wq + 4 * q;
            if (wc * 64 + wl < WC) {
                f32x4 v4 = *(const f32x4*)&tsl[r2 * 68 + wl];
                *(f32x4*)&orow[wl] = v4;
            }
        }
    }
}

extern "C" void kernel_launch(void* const* d_in, const int* in_sizes, int n_in,
                              void* d_out, int out_size, void* d_ws, size_t ws_size,
                              hipStream_t stream)
{
    const float* x      = (const float*)d_in[0];
    const float* w_qkv  = (const float*)d_in[1];
    const float* bias_t = (const float*)d_in[2];
    const float* w_h    = (const float*)d_in[3];
    const float* b_h    = (const float*)d_in[4];
    const float* w_v    = (const float*)d_in[5];
    const float* b_v    = (const float*)d_in[6];
    const float* w_dw   = (const float*)d_in[7];
    const float* bn_g   = (const float*)d_in[8];
    const float* bn_b   = (const float*)d_in[9];
    const float* bn_m   = (const float*)d_in[10];
    const float* bn_v   = (const float*)d_in[11];
    const float* w_pw   = (const float*)d_in[12];
    float* out = (float*)d_out;

    u16* wsu = (u16*)d_ws;
    const u16* XPu = wsu;
    const u16* ZPu = wsu + ZP_OFF / 2;
    const u16* WTu = wsu + WT_OFF / 2;
    const u16* WPu = wsu + WPW_OFF / 2;
    const u16* WQu = wsu + WQ_OFF / 2;
    const float* BFu = (const float*)(wsu + BIAS_OFF / 2);

    // wprep -> attn(MFMA, XPT out) -> halo -> sepconv(MFMA, bf16 P) -> dwbn -> pw
    wprep_kernel<<<5984, 256, 0, stream>>>(w_h, w_v, w_pw, w_qkv, bias_t, wsu);
    attn_mfma<<<2048, 256, 0, stream>>>(x, WQu, BFu, wsu);
    halo_kernel<<<6048, 256, 0, stream>>>(wsu);
    sepconv_mfma<<<504, 512, 0, stream>>>(XPu, WTu, ZPu, b_h, b_v, (u16*)d_out);
    dwbn_kernel<<<dim3(4, 16, 512), 256, 0, stream>>>((const u16*)d_out, w_dw, bn_g, bn_b,
                                                      bn_m, bn_v, (__hip_bfloat16*)d_ws);
    pw_mfma<<<504, 512, 0, stream>>>(wsu, WPu, out);
}